// Round 2
// baseline (1262.273 us; speedup 1.0000x reference)
//
#include <hip/hip_runtime.h>
#include <hip/hip_bf16.h>
#include <stdint.h>

#define D_MODEL 1024
#define HDIM    4096
#define NE      8

typedef __attribute__((ext_vector_type(8))) short short8;
typedef __attribute__((ext_vector_type(4))) float f32x4;
typedef __attribute__((ext_vector_type(2))) __bf16 bf16x2;
typedef __attribute__((ext_vector_type(4))) unsigned int uint4v;
typedef __attribute__((ext_vector_type(2))) unsigned int uint2v;

__device__ inline unsigned pk2(float a, float b) {
  bf16x2 v; v[0] = (__bf16)a; v[1] = (__bf16)b;
  return __builtin_bit_cast(unsigned, v);
}
__device__ inline unsigned short f2bf(float a) {
  __bf16 v = (__bf16)a;
  return __builtin_bit_cast(unsigned short, v);
}
// async global->LDS, 16B per lane; LDS dest = (wave-uniform base) + lane*16
__device__ inline void async16(const void* g, void* l) {
  __builtin_amdgcn_global_load_lds(
      (const __attribute__((address_space(1))) unsigned int*)g,
      (__attribute__((address_space(3))) unsigned int*)l, 16, 0, 0);
}

// ---------------- gating: one block per token (also emits bf16 x) ----------------
__global__ __launch_bounds__(256) void gate_kernel(
    const float* __restrict__ x, const float* __restrict__ gw,
    int* __restrict__ counts, int* __restrict__ tk_e, float* __restrict__ tk_g,
    unsigned short* __restrict__ xbf)
{
  const int t = blockIdx.x;
  const int tid = threadIdx.x;
  const float4 xv = ((const float4*)(x + (size_t)t * D_MODEL))[tid];
  if (xbf) {
    uint2v p; p[0] = pk2(xv.x, xv.y); p[1] = pk2(xv.z, xv.w);
    ((uint2v*)(xbf + (size_t)t * D_MODEL))[tid] = p;
  }
  float part[NE];
#pragma unroll
  for (int e = 0; e < NE; ++e) {
    const float4 gv = ((const float4*)(gw + e * D_MODEL))[tid];
    part[e] = xv.x * gv.x + xv.y * gv.y + xv.z * gv.z + xv.w * gv.w;
  }
#pragma unroll
  for (int off = 32; off > 0; off >>= 1)
#pragma unroll
    for (int e = 0; e < NE; ++e) part[e] += __shfl_down(part[e], off, 64);
  __shared__ float red[4][NE];
  const int wid = tid >> 6, lane = tid & 63;
  if (lane == 0)
    for (int e = 0; e < NE; ++e) red[wid][e] = part[e];
  __syncthreads();
  if (tid == 0) {
    float lg[NE];
    for (int e = 0; e < NE; ++e) lg[e] = red[0][e] + red[1][e] + red[2][e] + red[3][e];
    int e0 = 0;
    for (int e = 1; e < NE; ++e) if (lg[e] > lg[e0]) e0 = e;
    int e1 = (e0 == 0) ? 1 : 0;
    for (int e = 0; e < NE; ++e) { if (e == e0) continue; if (lg[e] > lg[e1]) e1 = e; }
    const float g0 = 1.0f / (1.0f + expf(lg[e1] - lg[e0]));
    tk_e[2*t] = e0; tk_e[2*t+1] = e1;
    tk_g[2*t] = g0; tk_g[2*t+1] = 1.0f - g0;
    atomicAdd(&counts[e0], 1);
    atomicAdd(&counts[e1], 1);
  }
}

__global__ void prefix_kernel(const int* __restrict__ counts,
                              int* __restrict__ cursor, int* __restrict__ offsets) {
  if (threadIdx.x == 0) {
    int s = 0;
    for (int e = 0; e < NE; ++e) { offsets[e] = s; s += counts[e]; cursor[e] = 0; }
  }
}

__global__ __launch_bounds__(256) void place_kernel(
    const int* __restrict__ tk_e, const float* __restrict__ tk_g,
    const int* __restrict__ offsets, int* __restrict__ cursor,
    int* __restrict__ token_of, float* __restrict__ gate_of, int T)
{
  const int t = blockIdx.x * 256 + threadIdx.x;
  if (t >= T) return;
  for (int k = 0; k < 2; ++k) {
    const int e = tk_e[2*t + k];
    const int pos = offsets[e] + atomicAdd(&cursor[e], 1);
    token_of[pos] = t;
    gate_of[pos] = tk_g[2*t + k];
  }
}

// ---------------- fp32 -> bf16 bulk convert ----------------
__global__ __launch_bounds__(256) void convert_kernel(
    const float* __restrict__ src, unsigned short* __restrict__ dst, long n4)
{
  long i = (long)blockIdx.x * 256 + threadIdx.x;
  const long stride = (long)gridDim.x * 256;
  for (; i < n4; i += stride) {
    const float4 v = ((const float4*)src)[i];
    uint2v p; p[0] = pk2(v.x, v.y); p[1] = pk2(v.z, v.w);
    ((uint2v*)dst)[i] = p;
  }
}

// ---------------- GEMM1: h[p,f] = relu( x[tok(p),:] . w1[e][f,:] ) ----------------
// grid: (x = token-tile [fastest], y = f-tile, z = expert) for L2/LLC weight reuse
template<bool ABF, bool BBF>
__global__ __launch_bounds__(256) void gemm1_t(
    const float* __restrict__ xf, const unsigned short* __restrict__ xb,
    const float* __restrict__ w1f, const unsigned short* __restrict__ w1b,
    const int* __restrict__ counts, const int* __restrict__ offsets,
    const int* __restrict__ token_of, unsigned short* __restrict__ h)
{
  const int e = blockIdx.z;
  const int ne = counts[e];
  const int zt = blockIdx.x;
  if (zt * 128 >= ne) return;
  const int off = offsets[e];
  const int p0 = off + zt * 128, pend = off + ne;
  const int f0 = blockIdx.y * 128;

  __shared__ __align__(16) short As[128 * 32];
  __shared__ __align__(16) short Bs[128 * 32];

  const int tid = threadIdx.x, lane = tid & 63, wid = tid >> 6;
  const int wm = (wid & 1) * 64, wn = (wid >> 1) * 64;
  const int lr = lane & 15, lq = lane >> 4;

  // staging addresses
  const unsigned short* aSrc0 = nullptr; const unsigned short* aSrc1 = nullptr;
  short* aDst0 = nullptr; short* aDst1 = nullptr;
  const float* aptrF = nullptr;
  if (ABF) {
    const int r0 = wid * 32 + (lane >> 2), r1 = r0 + 16;
    int i0 = p0 + r0; if (i0 >= pend) i0 = pend - 1;
    int i1 = p0 + r1; if (i1 >= pend) i1 = pend - 1;
    aSrc0 = xb + (size_t)token_of[i0] * D_MODEL + (lane & 3) * 8;
    aSrc1 = xb + (size_t)token_of[i1] * D_MODEL + (lane & 3) * 8;
    aDst0 = As + (wid * 2 + 0) * 512;
    aDst1 = As + (wid * 2 + 1) * 512;
  } else {
    const int r = tid >> 1, ch = tid & 1;
    int ip = p0 + r; if (ip >= pend) ip = pend - 1;
    aptrF = xf + (size_t)token_of[ip] * D_MODEL + ch * 16;
  }
  const unsigned short* bSrc0 = nullptr; const unsigned short* bSrc1 = nullptr;
  short* bDst0 = nullptr; short* bDst1 = nullptr;
  const float* bptrF = nullptr;
  if (BBF) {
    const unsigned short* w1be = w1b + (size_t)e * ((size_t)HDIM * D_MODEL);
    const int r0 = wid * 32 + (lane >> 2), r1 = r0 + 16;
    bSrc0 = w1be + (size_t)(f0 + r0) * D_MODEL + (lane & 3) * 8;
    bSrc1 = w1be + (size_t)(f0 + r1) * D_MODEL + (lane & 3) * 8;
    bDst0 = Bs + (wid * 2 + 0) * 512;
    bDst1 = Bs + (wid * 2 + 1) * 512;
  } else {
    const float* w1fe = w1f + (size_t)e * ((size_t)HDIM * D_MODEL);
    const int r = tid >> 1, ch = tid & 1;
    bptrF = w1fe + (size_t)(f0 + r) * D_MODEL + ch * 16;
  }
  const int rM = tid >> 1, chM = tid & 1;

  f32x4 acc[4][4];
#pragma unroll
  for (int i = 0; i < 4; ++i)
#pragma unroll
    for (int j = 0; j < 4; ++j) acc[i][j] = (f32x4){0.f, 0.f, 0.f, 0.f};

  for (int kk = 0; kk < D_MODEL; kk += 32) {
    float4 a0, a1, a2, a3, b0, b1, b2, b3;
    if (!ABF) {
      a0 = *(const float4*)(aptrF + kk);     a1 = *(const float4*)(aptrF + kk + 4);
      a2 = *(const float4*)(aptrF + kk + 8); a3 = *(const float4*)(aptrF + kk + 12);
    }
    if (!BBF) {
      b0 = *(const float4*)(bptrF + kk);     b1 = *(const float4*)(bptrF + kk + 4);
      b2 = *(const float4*)(bptrF + kk + 8); b3 = *(const float4*)(bptrF + kk + 12);
    }
    __syncthreads();
    if (ABF) {
      async16(aSrc0 + kk, aDst0);
      async16(aSrc1 + kk, aDst1);
    } else {
      uint4v wa0 = {pk2(a0.x,a0.y), pk2(a0.z,a0.w), pk2(a1.x,a1.y), pk2(a1.z,a1.w)};
      uint4v wa1 = {pk2(a2.x,a2.y), pk2(a2.z,a2.w), pk2(a3.x,a3.y), pk2(a3.z,a3.w)};
      *(uint4v*)&As[rM * 32 + chM * 16]     = wa0;
      *(uint4v*)&As[rM * 32 + chM * 16 + 8] = wa1;
    }
    if (BBF) {
      async16(bSrc0 + kk, bDst0);
      async16(bSrc1 + kk, bDst1);
    } else {
      uint4v wb0 = {pk2(b0.x,b0.y), pk2(b0.z,b0.w), pk2(b1.x,b1.y), pk2(b1.z,b1.w)};
      uint4v wb1 = {pk2(b2.x,b2.y), pk2(b2.z,b2.w), pk2(b3.x,b3.y), pk2(b3.z,b3.w)};
      *(uint4v*)&Bs[rM * 32 + chM * 16]     = wb0;
      *(uint4v*)&Bs[rM * 32 + chM * 16 + 8] = wb1;
    }
    __syncthreads();
    short8 af[4], bfr[4];
#pragma unroll
    for (int i = 0; i < 4; ++i) af[i]  = *(const short8*)&As[(wm + i*16 + lr) * 32 + lq * 8];
#pragma unroll
    for (int j = 0; j < 4; ++j) bfr[j] = *(const short8*)&Bs[(wn + j*16 + lr) * 32 + lq * 8];
#pragma unroll
    for (int i = 0; i < 4; ++i)
#pragma unroll
      for (int j = 0; j < 4; ++j)
        acc[i][j] = __builtin_amdgcn_mfma_f32_16x16x32_bf16(af[i], bfr[j], acc[i][j], 0, 0, 0);
  }

#pragma unroll
  for (int i = 0; i < 4; ++i) {
#pragma unroll
    for (int g = 0; g < 4; ++g) {
      const int m = wm + i*16 + lq*4 + g;
      const int pp = p0 + m;
      if (pp < pend) {
        unsigned short* hrow = h + (size_t)pp * HDIM + f0 + wn + lr;
#pragma unroll
        for (int j = 0; j < 4; ++j) {
          float v = acc[i][j][g];
          v = v > 0.f ? v : 0.f;
          hrow[j*16] = f2bf(v);
        }
      }
    }
  }
}

// ---------------- GEMM2: out[tok(p),d] += gate(p) * h[p,:] . w2[e][d,:] ----------------
template<bool BBF>
__global__ __launch_bounds__(256) void gemm2_t(
    const unsigned short* __restrict__ h, const float* __restrict__ w2f,
    const unsigned short* __restrict__ w2b,
    const int* __restrict__ counts, const int* __restrict__ offsets,
    const int* __restrict__ token_of, const float* __restrict__ gate_of,
    float* __restrict__ out)
{
  const int e = blockIdx.z;
  const int ne = counts[e];
  const int zt = blockIdx.x;
  if (zt * 128 >= ne) return;
  const int off = offsets[e];
  const int p0 = off + zt * 128, pend = off + ne;
  const int d0 = blockIdx.y * 128;

  __shared__ __align__(16) short As[128 * 32];
  __shared__ __align__(16) short Bs[128 * 32];

  const int tid = threadIdx.x, lane = tid & 63, wid = tid >> 6;
  const int wm = (wid & 1) * 64, wn = (wid >> 1) * 64;
  const int lr = lane & 15, lq = lane >> 4;

  // A (h, bf16) always via async staging
  const int rA0 = wid * 32 + (lane >> 2), rA1 = rA0 + 16;
  int iA0 = p0 + rA0; if (iA0 >= pend) iA0 = pend - 1;
  int iA1 = p0 + rA1; if (iA1 >= pend) iA1 = pend - 1;
  const unsigned short* aSrc0 = h + (size_t)iA0 * HDIM + (lane & 3) * 8;
  const unsigned short* aSrc1 = h + (size_t)iA1 * HDIM + (lane & 3) * 8;
  short* aDst0 = As + (wid * 2 + 0) * 512;
  short* aDst1 = As + (wid * 2 + 1) * 512;

  const unsigned short* bSrc0 = nullptr; const unsigned short* bSrc1 = nullptr;
  short* bDst0 = nullptr; short* bDst1 = nullptr;
  const float* bptrF = nullptr;
  if (BBF) {
    const unsigned short* w2be = w2b + (size_t)e * ((size_t)D_MODEL * HDIM);
    bSrc0 = w2be + (size_t)(d0 + rA0) * HDIM + (lane & 3) * 8;
    bSrc1 = w2be + (size_t)(d0 + rA1) * HDIM + (lane & 3) * 8;
    bDst0 = Bs + (wid * 2 + 0) * 512;
    bDst1 = Bs + (wid * 2 + 1) * 512;
  } else {
    const float* w2fe = w2f + (size_t)e * ((size_t)D_MODEL * HDIM);
    bptrF = w2fe + (size_t)(d0 + (tid >> 1)) * HDIM + (tid & 1) * 16;
  }
  const int rM = tid >> 1, chM = tid & 1;

  f32x4 acc[4][4];
#pragma unroll
  for (int i = 0; i < 4; ++i)
#pragma unroll
    for (int j = 0; j < 4; ++j) acc[i][j] = (f32x4){0.f, 0.f, 0.f, 0.f};

  for (int kk = 0; kk < HDIM; kk += 32) {
    float4 b0, b1, b2, b3;
    if (!BBF) {
      b0 = *(const float4*)(bptrF + kk);     b1 = *(const float4*)(bptrF + kk + 4);
      b2 = *(const float4*)(bptrF + kk + 8); b3 = *(const float4*)(bptrF + kk + 12);
    }
    __syncthreads();
    async16(aSrc0 + kk, aDst0);
    async16(aSrc1 + kk, aDst1);
    if (BBF) {
      async16(bSrc0 + kk, bDst0);
      async16(bSrc1 + kk, bDst1);
    } else {
      uint4v wb0 = {pk2(b0.x,b0.y), pk2(b0.z,b0.w), pk2(b1.x,b1.y), pk2(b1.z,b1.w)};
      uint4v wb1 = {pk2(b2.x,b2.y), pk2(b2.z,b2.w), pk2(b3.x,b3.y), pk2(b3.z,b3.w)};
      *(uint4v*)&Bs[rM * 32 + chM * 16]     = wb0;
      *(uint4v*)&Bs[rM * 32 + chM * 16 + 8] = wb1;
    }
    __syncthreads();
    short8 af[4], bfr[4];
#pragma unroll
    for (int i = 0; i < 4; ++i) af[i]  = *(const short8*)&As[(wm + i*16 + lr) * 32 + lq * 8];
#pragma unroll
    for (int j = 0; j < 4; ++j) bfr[j] = *(const short8*)&Bs[(wn + j*16 + lr) * 32 + lq * 8];
#pragma unroll
    for (int i = 0; i < 4; ++i)
#pragma unroll
      for (int j = 0; j < 4; ++j)
        acc[i][j] = __builtin_amdgcn_mfma_f32_16x16x32_bf16(af[i], bfr[j], acc[i][j], 0, 0, 0);
  }

#pragma unroll
  for (int i = 0; i < 4; ++i) {
#pragma unroll
    for (int g = 0; g < 4; ++g) {
      const int m = wm + i*16 + lq*4 + g;
      const int pp = p0 + m;
      if (pp < pend) {
        const int tok = token_of[pp];
        const float gv = gate_of[pp];
        float* orow = out + (size_t)tok * D_MODEL + d0 + wn + lr;
#pragma unroll
        for (int j = 0; j < 4; ++j)
          atomicAdd(&orow[j*16], gv * acc[i][j][g]);
      }
    }
  }
}

extern "C" void kernel_launch(void* const* d_in, const int* in_sizes, int n_in,
                              void* d_out, int out_size, void* d_ws, size_t ws_size,
                              hipStream_t stream)
{
  const float* x  = (const float*)d_in[0];
  const float* gw = (const float*)d_in[1];
  const float* w1 = (const float*)d_in[2];
  const float* w2 = (const float*)d_in[3];
  float* out = (float*)d_out;
  const int T = in_sizes[0] / D_MODEL;   // 8192 tokens

  char* wsb = (char*)d_ws;
  // routing block at [0, 1MiB)
  int*   counts   = (int*)wsb;                 // [8]
  int*   cursor   = counts + 8;                // [8]
  int*   offsets  = cursor + 8;                // [8]
  int*   tk_e     = offsets + 8;               // [2T]
  float* tk_g     = (float*)(tk_e + 2*T);      // [2T]
  int*   token_of = (int*)(tk_g + 2*T);        // [2T]
  float* gate_of  = (float*)(token_of + 2*T);  // [2T]

  const size_t MB = 1u << 20;
  const size_t xbf_sz = (size_t)T * D_MODEL * 2;                 // 16 MiB
  const size_t wbf_sz = (size_t)NE * HDIM * D_MODEL * 2;         // 64 MiB
  const size_t h_sz   = (size_t)(2*T) * HDIM * 2;                // 128 MiB

  const bool tierB = ws_size >= MB + xbf_sz + h_sz;              // >=145 MiB
  const bool tierA = ws_size >= MB + xbf_sz + 2*wbf_sz + h_sz;   // >=273 MiB

  unsigned short* xbf = tierB ? (unsigned short*)(wsb + MB) : nullptr;
  unsigned short* w1b = tierA ? (unsigned short*)(wsb + MB + xbf_sz) : nullptr;
  unsigned short* w2b = tierA ? (unsigned short*)(wsb + MB + xbf_sz + wbf_sz) : nullptr;
  unsigned short* h;
  if (tierA)      h = (unsigned short*)(wsb + MB + xbf_sz + 2*wbf_sz);
  else if (tierB) h = (unsigned short*)(wsb + MB + xbf_sz);
  else            h = (unsigned short*)(wsb + MB);

  hipMemsetAsync(d_ws, 0, 96, stream);
  hipMemsetAsync(d_out, 0, (size_t)out_size * sizeof(float), stream);

  gate_kernel<<<T, 256, 0, stream>>>(x, gw, counts, tk_e, tk_g, xbf);
  prefix_kernel<<<1, 64, 0, stream>>>(counts, cursor, offsets);
  place_kernel<<<(T + 255) / 256, 256, 0, stream>>>(tk_e, tk_g, offsets, cursor,
                                                    token_of, gate_of, T);
  if (tierA) {
    const long n4 = (long)NE * HDIM * D_MODEL / 4;
    convert_kernel<<<4096, 256, 0, stream>>>(w1, w1b, n4);
    convert_kernel<<<4096, 256, 0, stream>>>(w2, w2b, n4);
  }

  const int maxz = (T + 127) / 128;  // worst-case token tiles per expert
  dim3 g1(maxz, HDIM / 128, NE);     // token-tile fastest for weight-slice reuse
  dim3 g2(maxz, D_MODEL / 128, NE);
  if (tierA) {
    gemm1_t<true, true><<<g1, 256, 0, stream>>>(x, xbf, w1, w1b, counts, offsets, token_of, h);
    gemm2_t<true><<<g2, 256, 0, stream>>>(h, w2, w2b, counts, offsets, token_of, gate_of, out);
  } else if (tierB) {
    gemm1_t<true, false><<<g1, 256, 0, stream>>>(x, xbf, w1, w1b, counts, offsets, token_of, h);
    gemm2_t<false><<<g2, 256, 0, stream>>>(h, w2, w2b, counts, offsets, token_of, gate_of, out);
  } else {
    gemm1_t<false, false><<<g1, 256, 0, stream>>>(x, xbf, w1, w1b, counts, offsets, token_of, h);
    gemm2_t<false><<<g2, 256, 0, stream>>>(h, w2, w2b, counts, offsets, token_of, gate_of, out);
  }
}

// Round 3
// 1058.468 us; speedup vs baseline: 1.1925x; 1.1925x over previous
//
#include <hip/hip_runtime.h>
#include <hip/hip_bf16.h>
#include <stdint.h>

#define D_MODEL 1024
#define HDIM    4096
#define NE      8
#define MAXTILES 136   // 2T/128 + NE worst case (T=8192)

typedef __attribute__((ext_vector_type(8))) short short8;
typedef __attribute__((ext_vector_type(4))) float f32x4;
typedef __attribute__((ext_vector_type(2))) __bf16 bf16x2;
typedef __attribute__((ext_vector_type(4))) unsigned int uint4v;
typedef __attribute__((ext_vector_type(2))) unsigned int uint2v;

__device__ inline unsigned pk2(float a, float b) {
  bf16x2 v; v[0] = (__bf16)a; v[1] = (__bf16)b;
  return __builtin_bit_cast(unsigned, v);
}
__device__ inline unsigned short f2bf(float a) {
  __bf16 v = (__bf16)a;
  return __builtin_bit_cast(unsigned short, v);
}
// async global->LDS, 16B per lane; LDS dest = (wave-uniform base) + lane*16
__device__ inline void async16(const void* g, void* l) {
  __builtin_amdgcn_global_load_lds(
      (const __attribute__((address_space(1))) unsigned int*)g,
      (__attribute__((address_space(3))) unsigned int*)l, 16, 0, 0);
}

// ---------------- gating: one block per token (also emits bf16 x) ----------------
__global__ __launch_bounds__(256) void gate_kernel(
    const float* __restrict__ x, const float* __restrict__ gw,
    int* __restrict__ counts, int* __restrict__ tk_e, float* __restrict__ tk_g,
    unsigned short* __restrict__ xbf)
{
  const int t = blockIdx.x;
  const int tid = threadIdx.x;
  const float4 xv = ((const float4*)(x + (size_t)t * D_MODEL))[tid];
  if (xbf) {
    uint2v p; p[0] = pk2(xv.x, xv.y); p[1] = pk2(xv.z, xv.w);
    ((uint2v*)(xbf + (size_t)t * D_MODEL))[tid] = p;
  }
  float part[NE];
#pragma unroll
  for (int e = 0; e < NE; ++e) {
    const float4 gv = ((const float4*)(gw + e * D_MODEL))[tid];
    part[e] = xv.x * gv.x + xv.y * gv.y + xv.z * gv.z + xv.w * gv.w;
  }
#pragma unroll
  for (int off = 32; off > 0; off >>= 1)
#pragma unroll
    for (int e = 0; e < NE; ++e) part[e] += __shfl_down(part[e], off, 64);
  __shared__ float red[4][NE];
  const int wid = tid >> 6, lane = tid & 63;
  if (lane == 0)
    for (int e = 0; e < NE; ++e) red[wid][e] = part[e];
  __syncthreads();
  if (tid == 0) {
    float lg[NE];
    for (int e = 0; e < NE; ++e) lg[e] = red[0][e] + red[1][e] + red[2][e] + red[3][e];
    int e0 = 0;
    for (int e = 1; e < NE; ++e) if (lg[e] > lg[e0]) e0 = e;
    int e1 = (e0 == 0) ? 1 : 0;
    for (int e = 0; e < NE; ++e) { if (e == e0) continue; if (lg[e] > lg[e1]) e1 = e; }
    const float g0 = 1.0f / (1.0f + expf(lg[e1] - lg[e0]));
    tk_e[2*t] = e0; tk_e[2*t+1] = e1;
    tk_g[2*t] = g0; tk_g[2*t+1] = 1.0f - g0;
    atomicAdd(&counts[e0], 1);
    atomicAdd(&counts[e1], 1);
  }
}

// prefix sums + dense tile-descriptor list (grid compaction)
__global__ void prefix_kernel(const int* __restrict__ counts,
                              int* __restrict__ cursor, int* __restrict__ offsets,
                              int* __restrict__ tiles, int* __restrict__ n_tiles) {
  if (threadIdx.x == 0) {
    int s = 0, n = 0;
    for (int e = 0; e < NE; ++e) {
      offsets[e] = s;
      const int nt = (counts[e] + 127) >> 7;
      for (int z = 0; z < nt; ++z) tiles[n++] = (e << 16) | z;
      s += counts[e];
      cursor[e] = 0;
    }
    *n_tiles = n;
  }
}

__global__ __launch_bounds__(256) void place_kernel(
    const int* __restrict__ tk_e, const float* __restrict__ tk_g,
    const int* __restrict__ offsets, int* __restrict__ cursor,
    int* __restrict__ token_of, float* __restrict__ gate_of, int T)
{
  const int t = blockIdx.x * 256 + threadIdx.x;
  if (t >= T) return;
  for (int k = 0; k < 2; ++k) {
    const int e = tk_e[2*t + k];
    const int pos = offsets[e] + atomicAdd(&cursor[e], 1);
    token_of[pos] = t;
    gate_of[pos] = tk_g[2*t + k];
  }
}

// ---------------- fp32 -> bf16 bulk convert ----------------
__global__ __launch_bounds__(256) void convert_kernel(
    const float* __restrict__ src, unsigned short* __restrict__ dst, long n4)
{
  long i = (long)blockIdx.x * 256 + threadIdx.x;
  const long stride = (long)gridDim.x * 256;
  for (; i < n4; i += stride) {
    const float4 v = ((const float4*)src)[i];
    uint2v p; p[0] = pk2(v.x, v.y); p[1] = pk2(v.z, v.w);
    ((uint2v*)dst)[i] = p;
  }
}

// ---------------- GEMM1: h[p,f] = relu( x[tok(p),:] . w1[e][f,:] ) ----------------
// grid.x = dense tile index (compacted); grid.y = f-tile
template<bool ABF, bool BBF>
__global__ __launch_bounds__(256) void gemm1_t(
    const float* __restrict__ xf, const unsigned short* __restrict__ xb,
    const float* __restrict__ w1f, const unsigned short* __restrict__ w1b,
    const int* __restrict__ counts, const int* __restrict__ offsets,
    const int* __restrict__ tiles, const int* __restrict__ n_tiles,
    const int* __restrict__ token_of, unsigned short* __restrict__ h)
{
  if ((int)blockIdx.x >= *n_tiles) return;
  const int desc = tiles[blockIdx.x];
  const int e = desc >> 16, zt = desc & 0xffff;
  const int ne = counts[e];
  const int off = offsets[e];
  const int p0 = off + zt * 128, pend = off + ne;
  const int f0 = blockIdx.y * 128;

  __shared__ __align__(16) short As[128 * 32];
  __shared__ __align__(16) short Bs[128 * 32];

  const int tid = threadIdx.x, lane = tid & 63, wid = tid >> 6;
  const int wm = (wid & 1) * 64, wn = (wid >> 1) * 64;
  const int lr = lane & 15, lq = lane >> 4;

  const unsigned short* aSrc0 = nullptr; const unsigned short* aSrc1 = nullptr;
  short* aDst0 = nullptr; short* aDst1 = nullptr;
  const float* aptrF = nullptr;
  if (ABF) {
    const int r0 = wid * 32 + (lane >> 2), r1 = r0 + 16;
    int i0 = p0 + r0; if (i0 >= pend) i0 = pend - 1;
    int i1 = p0 + r1; if (i1 >= pend) i1 = pend - 1;
    aSrc0 = xb + (size_t)token_of[i0] * D_MODEL + (lane & 3) * 8;
    aSrc1 = xb + (size_t)token_of[i1] * D_MODEL + (lane & 3) * 8;
    aDst0 = As + (wid * 2 + 0) * 512;
    aDst1 = As + (wid * 2 + 1) * 512;
  } else {
    const int r = tid >> 1, ch = tid & 1;
    int ip = p0 + r; if (ip >= pend) ip = pend - 1;
    aptrF = xf + (size_t)token_of[ip] * D_MODEL + ch * 16;
  }
  const unsigned short* bSrc0 = nullptr; const unsigned short* bSrc1 = nullptr;
  short* bDst0 = nullptr; short* bDst1 = nullptr;
  const float* bptrF = nullptr;
  if (BBF) {
    const unsigned short* w1be = w1b + (size_t)e * ((size_t)HDIM * D_MODEL);
    const int r0 = wid * 32 + (lane >> 2), r1 = r0 + 16;
    bSrc0 = w1be + (size_t)(f0 + r0) * D_MODEL + (lane & 3) * 8;
    bSrc1 = w1be + (size_t)(f0 + r1) * D_MODEL + (lane & 3) * 8;
    bDst0 = Bs + (wid * 2 + 0) * 512;
    bDst1 = Bs + (wid * 2 + 1) * 512;
  } else {
    const float* w1fe = w1f + (size_t)e * ((size_t)HDIM * D_MODEL);
    const int r = tid >> 1, ch = tid & 1;
    bptrF = w1fe + (size_t)(f0 + r) * D_MODEL + ch * 16;
  }
  const int rM = tid >> 1, chM = tid & 1;

  f32x4 acc[4][4];
#pragma unroll
  for (int i = 0; i < 4; ++i)
#pragma unroll
    for (int j = 0; j < 4; ++j) acc[i][j] = (f32x4){0.f, 0.f, 0.f, 0.f};

  for (int kk = 0; kk < D_MODEL; kk += 32) {
    float4 a0, a1, a2, a3, b0, b1, b2, b3;
    if (!ABF) {
      a0 = *(const float4*)(aptrF + kk);     a1 = *(const float4*)(aptrF + kk + 4);
      a2 = *(const float4*)(aptrF + kk + 8); a3 = *(const float4*)(aptrF + kk + 12);
    }
    if (!BBF) {
      b0 = *(const float4*)(bptrF + kk);     b1 = *(const float4*)(bptrF + kk + 4);
      b2 = *(const float4*)(bptrF + kk + 8); b3 = *(const float4*)(bptrF + kk + 12);
    }
    __syncthreads();
    if (ABF) {
      async16(aSrc0 + kk, aDst0);
      async16(aSrc1 + kk, aDst1);
    } else {
      uint4v wa0 = {pk2(a0.x,a0.y), pk2(a0.z,a0.w), pk2(a1.x,a1.y), pk2(a1.z,a1.w)};
      uint4v wa1 = {pk2(a2.x,a2.y), pk2(a2.z,a2.w), pk2(a3.x,a3.y), pk2(a3.z,a3.w)};
      *(uint4v*)&As[rM * 32 + chM * 16]     = wa0;
      *(uint4v*)&As[rM * 32 + chM * 16 + 8] = wa1;
    }
    if (BBF) {
      async16(bSrc0 + kk, bDst0);
      async16(bSrc1 + kk, bDst1);
    } else {
      uint4v wb0 = {pk2(b0.x,b0.y), pk2(b0.z,b0.w), pk2(b1.x,b1.y), pk2(b1.z,b1.w)};
      uint4v wb1 = {pk2(b2.x,b2.y), pk2(b2.z,b2.w), pk2(b3.x,b3.y), pk2(b3.z,b3.w)};
      *(uint4v*)&Bs[rM * 32 + chM * 16]     = wb0;
      *(uint4v*)&Bs[rM * 32 + chM * 16 + 8] = wb1;
    }
    __syncthreads();
    short8 af[4], bfr[4];
#pragma unroll
    for (int i = 0; i < 4; ++i) af[i]  = *(const short8*)&As[(wm + i*16 + lr) * 32 + lq * 8];
#pragma unroll
    for (int j = 0; j < 4; ++j) bfr[j] = *(const short8*)&Bs[(wn + j*16 + lr) * 32 + lq * 8];
#pragma unroll
    for (int i = 0; i < 4; ++i)
#pragma unroll
      for (int j = 0; j < 4; ++j)
        acc[i][j] = __builtin_amdgcn_mfma_f32_16x16x32_bf16(af[i], bfr[j], acc[i][j], 0, 0, 0);
  }

#pragma unroll
  for (int i = 0; i < 4; ++i) {
#pragma unroll
    for (int g = 0; g < 4; ++g) {
      const int m = wm + i*16 + lq*4 + g;
      const int pp = p0 + m;
      if (pp < pend) {
        unsigned short* hrow = h + (size_t)pp * HDIM + f0 + wn + lr;
#pragma unroll
        for (int j = 0; j < 4; ++j) {
          float v = acc[i][j][g];
          v = v > 0.f ? v : 0.f;
          hrow[j*16] = f2bf(v);
        }
      }
    }
  }
}

// ---------------- GEMM2: out[tok(p),d] += gate(p) * h[p,:] . w2[e][d,:] ----------------
template<bool BBF>
__global__ __launch_bounds__(256) void gemm2_t(
    const unsigned short* __restrict__ h, const float* __restrict__ w2f,
    const unsigned short* __restrict__ w2b,
    const int* __restrict__ counts, const int* __restrict__ offsets,
    const int* __restrict__ tiles, const int* __restrict__ n_tiles,
    const int* __restrict__ token_of, const float* __restrict__ gate_of,
    float* __restrict__ out)
{
  if ((int)blockIdx.x >= *n_tiles) return;
  const int desc = tiles[blockIdx.x];
  const int e = desc >> 16, zt = desc & 0xffff;
  const int ne = counts[e];
  const int off = offsets[e];
  const int p0 = off + zt * 128, pend = off + ne;
  const int d0 = blockIdx.y * 128;

  __shared__ __align__(16) short As[128 * 32];
  __shared__ __align__(16) short Bs[128 * 32];

  const int tid = threadIdx.x, lane = tid & 63, wid = tid >> 6;
  const int wm = (wid & 1) * 64, wn = (wid >> 1) * 64;
  const int lr = lane & 15, lq = lane >> 4;

  const int rA0 = wid * 32 + (lane >> 2), rA1 = rA0 + 16;
  int iA0 = p0 + rA0; if (iA0 >= pend) iA0 = pend - 1;
  int iA1 = p0 + rA1; if (iA1 >= pend) iA1 = pend - 1;
  const unsigned short* aSrc0 = h + (size_t)iA0 * HDIM + (lane & 3) * 8;
  const unsigned short* aSrc1 = h + (size_t)iA1 * HDIM + (lane & 3) * 8;
  short* aDst0 = As + (wid * 2 + 0) * 512;
  short* aDst1 = As + (wid * 2 + 1) * 512;

  const unsigned short* bSrc0 = nullptr; const unsigned short* bSrc1 = nullptr;
  short* bDst0 = nullptr; short* bDst1 = nullptr;
  const float* bptrF = nullptr;
  if (BBF) {
    const unsigned short* w2be = w2b + (size_t)e * ((size_t)D_MODEL * HDIM);
    bSrc0 = w2be + (size_t)(d0 + rA0) * HDIM + (lane & 3) * 8;
    bSrc1 = w2be + (size_t)(d0 + rA1) * HDIM + (lane & 3) * 8;
    bDst0 = Bs + (wid * 2 + 0) * 512;
    bDst1 = Bs + (wid * 2 + 1) * 512;
  } else {
    const float* w2fe = w2f + (size_t)e * ((size_t)D_MODEL * HDIM);
    bptrF = w2fe + (size_t)(d0 + (tid >> 1)) * HDIM + (tid & 1) * 16;
  }
  const int rM = tid >> 1, chM = tid & 1;

  f32x4 acc[4][4];
#pragma unroll
  for (int i = 0; i < 4; ++i)
#pragma unroll
    for (int j = 0; j < 4; ++j) acc[i][j] = (f32x4){0.f, 0.f, 0.f, 0.f};

  for (int kk = 0; kk < HDIM; kk += 32) {
    float4 b0, b1, b2, b3;
    if (!BBF) {
      b0 = *(const float4*)(bptrF + kk);     b1 = *(const float4*)(bptrF + kk + 4);
      b2 = *(const float4*)(bptrF + kk + 8); b3 = *(const float4*)(bptrF + kk + 12);
    }
    __syncthreads();
    async16(aSrc0 + kk, aDst0);
    async16(aSrc1 + kk, aDst1);
    if (BBF) {
      async16(bSrc0 + kk, bDst0);
      async16(bSrc1 + kk, bDst1);
    } else {
      uint4v wb0 = {pk2(b0.x,b0.y), pk2(b0.z,b0.w), pk2(b1.x,b1.y), pk2(b1.z,b1.w)};
      uint4v wb1 = {pk2(b2.x,b2.y), pk2(b2.z,b2.w), pk2(b3.x,b3.y), pk2(b3.z,b3.w)};
      *(uint4v*)&Bs[rM * 32 + chM * 16]     = wb0;
      *(uint4v*)&Bs[rM * 32 + chM * 16 + 8] = wb1;
    }
    __syncthreads();
    short8 af[4], bfr[4];
#pragma unroll
    for (int i = 0; i < 4; ++i) af[i]  = *(const short8*)&As[(wm + i*16 + lr) * 32 + lq * 8];
#pragma unroll
    for (int j = 0; j < 4; ++j) bfr[j] = *(const short8*)&Bs[(wn + j*16 + lr) * 32 + lq * 8];
#pragma unroll
    for (int i = 0; i < 4; ++i)
#pragma unroll
      for (int j = 0; j < 4; ++j)
        acc[i][j] = __builtin_amdgcn_mfma_f32_16x16x32_bf16(af[i], bfr[j], acc[i][j], 0, 0, 0);
  }

#pragma unroll
  for (int i = 0; i < 4; ++i) {
#pragma unroll
    for (int g = 0; g < 4; ++g) {
      const int m = wm + i*16 + lq*4 + g;
      const int pp = p0 + m;
      if (pp < pend) {
        const int tok = token_of[pp];
        const float gv = gate_of[pp];
        float* orow = out + (size_t)tok * D_MODEL + d0 + wn + lr;
#pragma unroll
        for (int j = 0; j < 4; ++j)
          atomicAdd(&orow[j*16], gv * acc[i][j][g]);
      }
    }
  }
}

extern "C" void kernel_launch(void* const* d_in, const int* in_sizes, int n_in,
                              void* d_out, int out_size, void* d_ws, size_t ws_size,
                              hipStream_t stream)
{
  const float* x  = (const float*)d_in[0];
  const float* gw = (const float*)d_in[1];
  const float* w1 = (const float*)d_in[2];
  const float* w2 = (const float*)d_in[3];
  float* out = (float*)d_out;
  const int T = in_sizes[0] / D_MODEL;   // 8192 tokens

  char* wsb = (char*)d_ws;
  // routing block at [0, 1MiB)
  int*   counts   = (int*)wsb;                 // [8]
  int*   cursor   = counts + 8;                // [8]
  int*   offsets  = cursor + 8;                // [8]
  int*   n_tiles  = offsets + 8;               // [1]
  int*   tiles    = n_tiles + 1;               // [MAXTILES]
  int*   tk_e     = tiles + MAXTILES;          // [2T]
  float* tk_g     = (float*)(tk_e + 2*T);      // [2T]
  int*   token_of = (int*)(tk_g + 2*T);        // [2T]
  float* gate_of  = (float*)(token_of + 2*T);  // [2T]

  const size_t MB = 1u << 20;
  const size_t xbf_sz = (size_t)T * D_MODEL * 2;                 // 16 MiB
  const size_t wbf_sz = (size_t)NE * HDIM * D_MODEL * 2;         // 64 MiB
  const size_t h_sz   = (size_t)(2*T) * HDIM * 2;                // 128 MiB

  const bool tierB = ws_size >= MB + xbf_sz + h_sz;              // >=145 MiB
  const bool tierA = ws_size >= MB + xbf_sz + 2*wbf_sz + h_sz;   // >=273 MiB

  unsigned short* xbf = tierB ? (unsigned short*)(wsb + MB) : nullptr;
  unsigned short* w1b = tierA ? (unsigned short*)(wsb + MB + xbf_sz) : nullptr;
  unsigned short* w2b = tierA ? (unsigned short*)(wsb + MB + xbf_sz + wbf_sz) : nullptr;
  unsigned short* h;
  if (tierA)      h = (unsigned short*)(wsb + MB + xbf_sz + 2*wbf_sz);
  else if (tierB) h = (unsigned short*)(wsb + MB + xbf_sz);
  else            h = (unsigned short*)(wsb + MB);

  hipMemsetAsync(d_ws, 0, 128, stream);
  hipMemsetAsync(d_out, 0, (size_t)out_size * sizeof(float), stream);

  gate_kernel<<<T, 256, 0, stream>>>(x, gw, counts, tk_e, tk_g, xbf);
  prefix_kernel<<<1, 64, 0, stream>>>(counts, cursor, offsets, tiles, n_tiles);
  place_kernel<<<(T + 255) / 256, 256, 0, stream>>>(tk_e, tk_g, offsets, cursor,
                                                    token_of, gate_of, T);
  if (tierA) {
    const long n4 = (long)NE * HDIM * D_MODEL / 4;
    convert_kernel<<<4096, 256, 0, stream>>>(w1, w1b, n4);
    convert_kernel<<<4096, 256, 0, stream>>>(w2, w2b, n4);
  }

  dim3 g1(MAXTILES, HDIM / 128, 1);   // dense tile idx fastest; dead tail contiguous
  dim3 g2(MAXTILES, D_MODEL / 128, 1);
  if (tierA) {
    gemm1_t<true, true><<<g1, 256, 0, stream>>>(x, xbf, w1, w1b, counts, offsets,
                                                tiles, n_tiles, token_of, h);
    gemm2_t<true><<<g2, 256, 0, stream>>>(h, w2, w2b, counts, offsets,
                                          tiles, n_tiles, token_of, gate_of, out);
  } else if (tierB) {
    gemm1_t<true, false><<<g1, 256, 0, stream>>>(x, xbf, w1, w1b, counts, offsets,
                                                 tiles, n_tiles, token_of, h);
    gemm2_t<false><<<g2, 256, 0, stream>>>(h, w2, w2b, counts, offsets,
                                           tiles, n_tiles, token_of, gate_of, out);
  } else {
    gemm1_t<false, false><<<g1, 256, 0, stream>>>(x, xbf, w1, w1b, counts, offsets,
                                                  tiles, n_tiles, token_of, h);
    gemm2_t<false><<<g2, 256, 0, stream>>>(h, w2, w2b, counts, offsets,
                                           tiles, n_tiles, token_of, gate_of, out);
  }
}